// Round 3
// baseline (228.862 us; speedup 1.0000x reference)
//
#include <hip/hip_runtime.h>

typedef __bf16 bf16x8 __attribute__((ext_vector_type(8)));
typedef float f32x4 __attribute__((ext_vector_type(4)));
typedef unsigned short u16;
typedef unsigned int u32;
typedef u16 u16x8 __attribute__((ext_vector_type(8)));
typedef u16 u16x4 __attribute__((ext_vector_type(4)));
typedef u32 u32x4 __attribute__((ext_vector_type(4)));

__device__ __forceinline__ u16 f2bf(float f) {
    u32 u = __builtin_bit_cast(u32, f);
    u += 0x7fffu + ((u >> 16) & 1u);   // RNE
    return (u16)(u >> 16);
}
__device__ __forceinline__ float bf2f(u16 v) {
    return __builtin_bit_cast(float, (u32)v << 16);
}
__device__ __forceinline__ u32 pack2(float a, float b) {
    return (u32)f2bf(a) | ((u32)f2bf(b) << 16);
}
__device__ __forceinline__ f32x4 mfma16(u16x8 a, u16x8 b, f32x4 c) {
    return __builtin_amdgcn_mfma_f32_16x16x32_bf16(
        __builtin_bit_cast(bf16x8, a), __builtin_bit_cast(bf16x8, b), c, 0, 0, 0);
}

// ---------------------------------------------------------------------------
// Kernel 0: transpose W fp32 [512][128] -> Wt bf16 [3][128][512]
// ---------------------------------------------------------------------------
__global__ __launch_bounds__(256) void transpose_w(
    const float* __restrict__ Wq, const float* __restrict__ Wk,
    const float* __restrict__ Wv, u16* __restrict__ wt)
{
    int w = blockIdx.x >> 5;
    int local = ((blockIdx.x & 31) << 8) + threadIdx.x;
    int n = local & 127;
    int k0 = (local >> 7) << 3;
    const float* W = (w == 0) ? Wq : (w == 1 ? Wk : Wv);
    u16x8 v;
    #pragma unroll
    for (int i = 0; i < 8; ++i) v[i] = f2bf(W[(size_t)(k0 + i) * 128 + n]);
    *(u16x8*)&wt[((size_t)w * 128 + n) * 512 + k0] = v;
}

// ---------------------------------------------------------------------------
// Kernel 1: QKV projection, LDS-free. Wave owns 16 rows x 128 cols, K=512.
// q pre-scaled by 1/sqrt(128); v written TRANSPOSED [B][128][S].
// ---------------------------------------------------------------------------
__global__ __launch_bounds__(256) void qkv_proj(
    const float* __restrict__ x, const u16* __restrict__ wt,
    u16* __restrict__ qb, u16* __restrict__ kb, u16* __restrict__ vt)
{
    const int DIN = 512, D = 128;
    const int tid = threadIdx.x, lane = tid & 63, wid = tid >> 6;
    const int g = lane >> 4, l16 = lane & 15;
    const int widx = blockIdx.y;
    const int r0 = blockIdx.x * 64 + wid * 16;
    const u16* W = wt + (size_t)widx * 128 * 512;

    const f32x4 fz = {0.f, 0.f, 0.f, 0.f};
    f32x4 acc[8];
    #pragma unroll
    for (int n = 0; n < 8; ++n) acc[n] = fz;

    const float* xr = x + (size_t)(r0 + l16) * DIN + 8 * g;
    #pragma unroll 4
    for (int k0 = 0; k0 < DIN; k0 += 32) {
        float4 xa = *(const float4*)(xr + k0);
        float4 xb = *(const float4*)(xr + k0 + 4);
        u32x4 ad = { pack2(xa.x, xa.y), pack2(xa.z, xa.w),
                     pack2(xb.x, xb.y), pack2(xb.z, xb.w) };
        u16x8 a = __builtin_bit_cast(u16x8, ad);
        #pragma unroll
        for (int n = 0; n < 8; ++n) {
            u16x8 b = *(const u16x8*)&W[(size_t)(n * 16 + l16) * 512 + k0 + 8 * g];
            acc[n] = mfma16(a, b, acc[n]);
        }
    }

    if (widx < 2) {
        const float scale = (widx == 0) ? 0.08838834764831845f : 1.0f;
        u16* out = (widx == 0) ? qb : kb;
        #pragma unroll
        for (int n = 0; n < 8; ++n) {
            u16x4 pv;
            #pragma unroll
            for (int r = 0; r < 4; ++r) pv[r] = f2bf(acc[n][r] * scale);
            #pragma unroll
            for (int r = 0; r < 4; ++r)
                out[(size_t)(r0 + g * 4 + r) * D + n * 16 + l16] = pv[r];
        }
    } else {
        const int b = r0 >> 12, s = r0 & 4095;
        #pragma unroll
        for (int n = 0; n < 8; ++n) {
            u16x4 pv;
            #pragma unroll
            for (int r = 0; r < 4; ++r) pv[r] = f2bf(acc[n][r]);
            *(u16x4*)&vt[((size_t)b * 128 + n * 16 + l16) * 4096 + s + g * 4] = pv;
        }
    }
}

// ---------------------------------------------------------------------------
// Kernel 2: causal flash attention, 1 wave = 16 q-rows, exact-packed split-K.
// No LDS, no barriers. 4 waves/block share (batch, K-chunk) -> L1 reuse.
// XCD-bijective block mapping: XCD pair {2b,2b+1} serves batch b.
// ---------------------------------------------------------------------------
__global__ __launch_bounds__(256) void attn3(
    const u16* __restrict__ qb, const u16* __restrict__ kb,
    const u16* __restrict__ vt, float* __restrict__ out,
    u16* __restrict__ po, float* __restrict__ pml,
    int C, int Gsh, int NG, int Jb)
{
    const int S = 4096, D = 128;
    const int tid = threadIdx.x, lane = tid & 63, wid = tid >> 6;
    const int g = lane >> 4, l16 = lane & 15;

    // ---- job decode: block -> (batch, 4 consecutive jobs) ----
    const int xcd = blockIdx.x & 7, kkb = blockIdx.x >> 3;
    const int b = xcd >> 1;
    const int jb = (((xcd & 1) * (Jb >> 3)) + kkb) * 4 + wid;
    const int G = 1 << Gsh;
    int i = 0;
    #pragma unroll 1
    for (; i + 1 < NG; ++i) {
        int nxt = (G * (i + 1) * (i + 2)) >> 1;
        if (jb < nxt) break;
    }
    const int off = jb - ((G * i * (i + 1)) >> 1);
    const int c = off >> Gsh;
    const int qt = (i << Gsh) + (off & (G - 1));
    const int q0 = qt * 16;
    const int klen = q0 + 16;
    const int k_lo = c * C;
    const int k_hi = min(k_lo + C, klen);
    const int nch = i + 1;

    const u16* qB = qb + (size_t)b * S * D;
    const u16* kB = kb + (size_t)b * S * D;
    const u16* vB = vt + (size_t)b * D * S;   // [e][s]

    u16x8 qf[4];
    #pragma unroll
    for (int ds = 0; ds < 4; ++ds)
        qf[ds] = *(const u16x8*)&qB[(size_t)(q0 + l16) * D + ds * 32 + 8 * g];

    const f32x4 fz = {0.f, 0.f, 0.f, 0.f};
    f32x4 o[8];
    #pragma unroll
    for (int e = 0; e < 8; ++e) o[e] = fz;
    float m = -3e38f, l = 0.0f;

    const int srcA = l16 + ((g & 1) << 5);
    const int srcB = srcA + 16;
    const bool hiSel = (g >= 2);
    const int qg = q0 + l16;

    for (int k0 = k_lo; k0 < k_hi; k0 += 64) {
        // ---- S^T = K * Q^T ----
        f32x4 st[4];
        #pragma unroll
        for (int kt = 0; kt < 4; ++kt) {
            st[kt] = fz;
            #pragma unroll
            for (int ds = 0; ds < 4; ++ds) {
                u16x8 kf = *(const u16x8*)&kB[(size_t)(k0 + kt * 16 + l16) * D + ds * 32 + 8 * g];
                st[kt] = mfma16(kf, qf[ds], st[kt]);
            }
        }
        // ---- causal mask (diagonal tiles only) ----
        if (k0 + 63 > q0) {
            #pragma unroll
            for (int kt = 0; kt < 4; ++kt)
                #pragma unroll
                for (int r = 0; r < 4; ++r) {
                    int kg = k0 + kt * 16 + g * 4 + r;
                    if (kg > qg) st[kt][r] = -1e30f;
                }
        }
        // ---- online softmax (lane owns row qg; partners at lane^16, lane^32) ----
        float pm = -3e38f;
        #pragma unroll
        for (int kt = 0; kt < 4; ++kt)
            pm = fmaxf(pm, fmaxf(fmaxf(st[kt][0], st[kt][1]), fmaxf(st[kt][2], st[kt][3])));
        pm = fmaxf(pm, __shfl_xor(pm, 16));
        pm = fmaxf(pm, __shfl_xor(pm, 32));
        float mnew = fmaxf(m, pm);
        float alpha = __expf(m - mnew);
        float lsum = 0.f;
        u32 pkd[4][2];
        #pragma unroll
        for (int kt = 0; kt < 4; ++kt) {
            float p0 = __expf(st[kt][0] - mnew), p1 = __expf(st[kt][1] - mnew);
            float p2 = __expf(st[kt][2] - mnew), p3 = __expf(st[kt][3] - mnew);
            lsum += (p0 + p1) + (p2 + p3);
            pkd[kt][0] = pack2(p0, p1);
            pkd[kt][1] = pack2(p2, p3);
        }
        lsum += __shfl_xor(lsum, 16);
        lsum += __shfl_xor(lsum, 32);
        l = l * alpha + lsum;
        m = mnew;
        #pragma unroll
        for (int e = 0; e < 8; ++e)
            #pragma unroll
            for (int r = 0; r < 4; ++r) o[e][r] *= alpha;

        // ---- P redistribution in-register + O^T += V^T * P^T ----
        #pragma unroll
        for (int ksel = 0; ksel < 2; ++ksel) {
            u32 lo0 = __shfl((int)pkd[2 * ksel][0], srcA), hi0 = __shfl((int)pkd[2 * ksel + 1][0], srcA);
            u32 lo1 = __shfl((int)pkd[2 * ksel][1], srcA), hi1 = __shfl((int)pkd[2 * ksel + 1][1], srcA);
            u32 lo2 = __shfl((int)pkd[2 * ksel][0], srcB), hi2 = __shfl((int)pkd[2 * ksel + 1][0], srcB);
            u32 lo3 = __shfl((int)pkd[2 * ksel][1], srcB), hi3 = __shfl((int)pkd[2 * ksel + 1][1], srcB);
            u32x4 dw = { hiSel ? hi0 : lo0, hiSel ? hi1 : lo1,
                         hiSel ? hi2 : lo2, hiSel ? hi3 : lo3 };
            u16x8 pf = __builtin_bit_cast(u16x8, dw);
            #pragma unroll
            for (int e = 0; e < 8; ++e) {
                u16x8 vf = *(const u16x8*)&vB[(size_t)(e * 16 + l16) * S + k0 + ksel * 32 + 8 * g];
                o[e] = mfma16(vf, pf, o[e]);
            }
        }
    }

    if (nch == 1) {
        const float inv = 1.0f / l;
        float* op = out + ((size_t)b * S + qg) * D;
        #pragma unroll
        for (int e = 0; e < 8; ++e) {
            f32x4 v = o[e];
            v[0] *= inv; v[1] *= inv; v[2] *= inv; v[3] *= inv;
            *(f32x4*)&op[e * 16 + g * 4] = v;
        }
    } else {
        const int slot = b * Jb + jb;
        u16* pp = po + ((size_t)slot * 16 + l16) * 128;
        #pragma unroll
        for (int e = 0; e < 8; ++e) {
            u16x4 pv;
            #pragma unroll
            for (int r = 0; r < 4; ++r) pv[r] = f2bf(o[e][r]);
            *(u16x4*)&pp[e * 16 + g * 4] = pv;
        }
        if (g == 0)
            ((float2*)pml)[(size_t)slot * 16 + l16] = make_float2(m, l);
    }
}

// ---------------------------------------------------------------------------
// Kernel 3: merge split-K partials (rows with qt >= G). 1 thread = 4 cols.
// Two-pass over pml (no runtime-indexed arrays -> no scratch).
// ---------------------------------------------------------------------------
__global__ __launch_bounds__(256) void merge3(
    const u16* __restrict__ po, const float* __restrict__ pml,
    float* __restrict__ out, int Gsh, int NG, int Jb, int rows_per_b)
{
    int gid = blockIdx.x * 256 + threadIdx.x;
    int colg = gid & 31;
    int r = gid >> 5;
    int b = r / rows_per_b;
    int rr = r - b * rows_per_b;
    int G = 1 << Gsh;
    int qt = (rr >> 4) + G;
    int qr = rr & 15;
    int i = qt >> Gsh;
    int nch = i + 1;
    int slot0 = b * Jb + ((G * i * (i + 1)) >> 1) + (qt & (G - 1));

    const float2* pml2 = (const float2*)pml;
    float ms = -3e38f;
    #pragma unroll 1
    for (int c = 0; c < nch; ++c) {
        float2 ml = pml2[(size_t)(slot0 + c * G) * 16 + qr];
        ms = fmaxf(ms, ml.x);
    }
    float den = 0.f;
    f32x4 num = {0.f, 0.f, 0.f, 0.f};
    #pragma unroll 1
    for (int c = 0; c < nch; ++c) {
        int slot = slot0 + c * G;
        float2 ml = pml2[(size_t)slot * 16 + qr];
        float w = __expf(ml.x - ms);
        den += w * ml.y;
        u16x4 pv = *(const u16x4*)&po[((size_t)slot * 16 + qr) * 128 + colg * 4];
        #pragma unroll
        for (int j = 0; j < 4; ++j) num[j] += w * bf2f(pv[j]);
    }
    float inv = 1.0f / den;
    f32x4 res = { num[0] * inv, num[1] * inv, num[2] * inv, num[3] * inv };
    *(f32x4*)&out[((size_t)b * 4096 + qt * 16 + qr) * 128 + colg * 4] = res;
}

extern "C" void kernel_launch(void* const* d_in, const int* in_sizes, int n_in,
                              void* d_out, int out_size, void* d_ws, size_t ws_size,
                              hipStream_t stream) {
    (void)in_sizes; (void)n_in; (void)out_size;
    const int B = 4, S = 4096, D = 128;
    const float* x  = (const float*)d_in[0];
    const float* Wq = (const float*)d_in[1];
    const float* Wk = (const float*)d_in[2];
    const float* Wv = (const float*)d_in[3];
    float* out = (float*)d_out;

    u16* qb = (u16*)d_ws;
    u16* kb = qb + (size_t)B * S * D;
    u16* vt = kb + (size_t)B * S * D;
    u16* wt = vt + (size_t)B * S * D;
    const size_t base = (size_t)B * S * D * 3 * 2 + (size_t)3 * 128 * 512 * 2; // 12,976,128 B

    // choose chunk size: slots = 4*Jb; po = slots*4096 B (bf16), pml = slots*128 B
    auto need = [base](size_t slots) { return base + slots * 4096 + slots * 128; };
    int C;
    if      (ws_size >= need(8704)) C = 256;
    else if (ws_size >= need(4608)) C = 512;
    else if (ws_size >= need(2560)) C = 1024;
    else                            C = 4096;   // no split
    const int G = C / 16;
    const int Gsh = __builtin_ctz((unsigned)G);
    const int NG = 4096 / C;
    const int Jb = G * NG * (NG + 1) / 2;

    u16*   po  = (u16*)((char*)d_ws + base);
    float* pml = (float*)((char*)d_ws + base + (size_t)4 * Jb * 4096);

    transpose_w<<<96, 256, 0, stream>>>(Wq, Wk, Wv, wt);
    qkv_proj<<<dim3(B * S / 64, 3), 256, 0, stream>>>(x, wt, qb, kb, vt);
    attn3<<<Jb, 256, 0, stream>>>(qb, kb, vt, out, po, pml, C, Gsh, NG, Jb);
    if (NG > 1) {
        const int rows_per_b = (256 - G) * 16;
        merge3<<<rows_per_b / 2, 256, 0, stream>>>(po, pml, out, Gsh, NG, Jb, rows_per_b);
    }
}

// Round 4
// 138.890 us; speedup vs baseline: 1.6478x; 1.6478x over previous
//
#include <hip/hip_runtime.h>

typedef __bf16 bf16x8 __attribute__((ext_vector_type(8)));
typedef float f32x4 __attribute__((ext_vector_type(4)));
typedef unsigned short u16;
typedef unsigned int u32;
typedef u16 u16x8 __attribute__((ext_vector_type(8)));
typedef u16 u16x4 __attribute__((ext_vector_type(4)));
typedef u32 u32x4 __attribute__((ext_vector_type(4)));

__device__ __forceinline__ u16 f2bf(float f) {
    u32 u = __builtin_bit_cast(u32, f);
    u += 0x7fffu + ((u >> 16) & 1u);   // RNE
    return (u16)(u >> 16);
}
__device__ __forceinline__ float bf2f(u16 v) {
    return __builtin_bit_cast(float, (u32)v << 16);
}
__device__ __forceinline__ u32 cvtpk(float a, float b) {   // lo=bf16(a), hi=bf16(b)
    u32 d;
    asm("v_cvt_pk_bf16_f32 %0, %1, %2" : "=v"(d) : "v"(a), "v"(b));
    return d;
}
__device__ __forceinline__ f32x4 mfma16(u16x8 a, u16x8 b, f32x4 c) {
    return __builtin_amdgcn_mfma_f32_16x16x32_bf16(
        __builtin_bit_cast(bf16x8, a), __builtin_bit_cast(bf16x8, b), c, 0, 0, 0);
}

// chunk-XOR LDS addressing for a [16][128] u16 tile (16B chunks, XOR row into chunk)
__device__ __forceinline__ int ldsAddr(int r, int c) {       // u16 index
    return r * 128 + (((c >> 3) ^ (r & 7)) << 3) + (c & 7);
}

// ---------------------------------------------------------------------------
// Kernel 0: W fp32 [512][128] -> Wf frag-major bf16.
// Wf[((widx*8+n)*16+ds)*64 + lane]*8 + j = W[ds*32+8g+j][n*16+l16] (lane=l16+16g)
// Wq pre-scaled by 1/sqrt(128)*log2(e)  (log2-domain softmax downstream).
// ---------------------------------------------------------------------------
__global__ __launch_bounds__(256) void prep_w(
    const float* __restrict__ Wq, const float* __restrict__ Wk,
    const float* __restrict__ Wv, u16* __restrict__ wf)
{
    int flat = blockIdx.x * 256 + threadIdx.x;     // 24576
    int widx = flat >> 13, rem = flat & 8191;
    int n = rem >> 10, ds = (rem >> 6) & 15, lane = rem & 63;
    int l16 = lane & 15, g = lane >> 4;
    const float* W = (widx == 0) ? Wq : (widx == 1 ? Wk : Wv);
    const float sc = (widx == 0) ? (0.08838834764831845f * 1.4426950408889634f) : 1.0f;
    u16x8 v;
    #pragma unroll
    for (int j = 0; j < 8; ++j)
        v[j] = f2bf(W[(size_t)(ds * 32 + 8 * g + j) * 128 + n * 16 + l16] * sc);
    *(u16x8*)&wf[(size_t)flat * 8] = v;
}

// ---------------------------------------------------------------------------
// Kernel 1: x fp32 -> xf frag-major bf16.
// xf[((rb*16+ds)*64+lane)*8 + j] = x[rb*16+l16][ds*32+8g+j]
// ---------------------------------------------------------------------------
__global__ __launch_bounds__(256) void prep_x(
    const float* __restrict__ x, u16* __restrict__ xf)
{
    __shared__ u16 T[16 * 512];
    const int rb = blockIdx.x, t = threadIdx.x;
    const int row = t >> 4, colb = (t & 15) * 32;
    const float* src = x + (size_t)(rb * 16 + row) * 512 + colb;
    #pragma unroll
    for (int i = 0; i < 4; ++i) {
        float4 va = *(const float4*)(src + i * 8);
        float4 vb = *(const float4*)(src + i * 8 + 4);
        u16x8 v;
        v[0] = f2bf(va.x); v[1] = f2bf(va.y); v[2] = f2bf(va.z); v[3] = f2bf(va.w);
        v[4] = f2bf(vb.x); v[5] = f2bf(vb.y); v[6] = f2bf(vb.z); v[7] = f2bf(vb.w);
        int chunk = ((colb >> 3) + i) ^ (row & 7);
        *(u16x8*)&T[row * 512 + chunk * 8] = v;
    }
    __syncthreads();
    #pragma unroll
    for (int ii = 0; ii < 4; ++ii) {
        int flatF = ii * 256 + t;
        int ds = flatF >> 6, lane = flatF & 63;
        int l16 = lane & 15, g = lane >> 4;
        int chunk = (4 * ds + g) ^ (l16 & 7);
        u16x8 v = *(const u16x8*)&T[l16 * 512 + chunk * 8];
        *(u16x8*)&xf[(((size_t)rb * 16 + ds) * 64 + lane) * 8] = v;
    }
}

// ---------------------------------------------------------------------------
// Kernel 2: QKV GEMM, frag-major in/out. Wave owns 32 rows (2 rb16) x 128 cols.
// Outputs: Qf/Kf frag-major (same layout fn as xf); Vf transposed-frag:
// Vf[(((kb*2+ksel)*8+e)*64 + g'*16 + l16')*8 + j] = V[kb*64+ksel*32+8g'+j][e*16+l16']
// ---------------------------------------------------------------------------
__global__ __launch_bounds__(256) void qkv2(
    const u16* __restrict__ xf, const u16* __restrict__ wf,
    u16* __restrict__ Qf, u16* __restrict__ Kf, u16* __restrict__ Vf)
{
    __shared__ u16 T4[4][16 * 128];
    const int tid = threadIdx.x, lane = tid & 63, wid = tid >> 6;
    const int g = lane >> 4, l16 = lane & 15;
    const int widx = blockIdx.y;
    const int rb0 = (blockIdx.x * 128 + wid * 32) >> 4;   // first 16-row block
    const u16* WfB = wf + (size_t)widx * 8192 * 8;
    u16* T = T4[wid];

    const f32x4 fz = {0.f, 0.f, 0.f, 0.f};
    f32x4 acc0[8], acc1[8];
    #pragma unroll
    for (int n = 0; n < 8; ++n) { acc0[n] = fz; acc1[n] = fz; }

    #pragma unroll 4
    for (int ds = 0; ds < 16; ++ds) {
        u16x8 a0 = *(const u16x8*)&xf[(((size_t)rb0 * 16 + ds) * 64 + lane) * 8];
        u16x8 a1 = *(const u16x8*)&xf[(((size_t)(rb0 + 1) * 16 + ds) * 64 + lane) * 8];
        #pragma unroll
        for (int n = 0; n < 8; ++n) {
            u16x8 b = *(const u16x8*)&WfB[((size_t)(n * 16 + ds) * 64 + lane) * 8];
            acc0[n] = mfma16(a0, b, acc0[n]);
            acc1[n] = mfma16(a1, b, acc1[n]);
        }
    }

    #pragma unroll
    for (int h = 0; h < 2; ++h) {
        const int rbg = rb0 + h;
        // bounce C/D tile into LDS (rows local 0..15, cols 0..127)
        #pragma unroll
        for (int n = 0; n < 8; ++n) {
            f32x4 a = h ? acc1[n] : acc0[n];
            #pragma unroll
            for (int r = 0; r < 4; ++r)
                T[ldsAddr(4 * g + r, n * 16 + l16)] = f2bf(a[r]);
        }
        if (widx < 2) {
            u16* dst = (widx == 0) ? Qf : Kf;
            #pragma unroll
            for (int ds = 0; ds < 4; ++ds) {
                int chunk = (4 * ds + g) ^ (l16 & 7);
                u16x8 v = *(const u16x8*)&T[l16 * 128 + chunk * 8];
                *(u16x8*)&dst[(((size_t)rbg * 4 + ds) * 64 + lane) * 8] = v;
            }
        } else {
            const int kb = rbg >> 2, ksel = (rbg >> 1) & 1, g0 = (rbg & 1) * 2;
            #pragma unroll
            for (int s = 0; s < 4; ++s) {
                int flat = s * 64 + lane;
                int e = flat >> 5, gg = (flat >> 4) & 1, l16p = flat & 15;
                u16x8 v;
                #pragma unroll
                for (int j = 0; j < 8; ++j)
                    v[j] = T[ldsAddr(8 * gg + j, e * 16 + l16p)];
                *(u16x8*)&Vf[((((size_t)kb * 2 + ksel) * 8 + e) * 64
                              + (g0 + gg) * 16 + l16p) * 8] = v;
            }
        }
        // h=1 reuses T; same-wave write/read ordering handled by lgkmcnt
    }
}

// ---------------------------------------------------------------------------
// Kernel 3: causal flash attention. 1 wave = 32 q-rows (2 halves), split-K.
// All fragment loads wave-contiguous (1 KB). log2-domain softmax, defer-rescale.
// ---------------------------------------------------------------------------
__global__ __launch_bounds__(256, 3) void attn4(
    const u16* __restrict__ Qf, const u16* __restrict__ Kf,
    const u16* __restrict__ Vf, float* __restrict__ out,
    u16* __restrict__ po, float2* __restrict__ pml,
    int C, int Gp, int NG, int Jb)
{
    const int tid = threadIdx.x, lane = tid & 63, wid = tid >> 6;
    const int g = lane >> 4, l16 = lane & 15;

    // job decode: XCD pair {2b,2b+1} serves batch b; 4 consecutive jobs per block
    const int xcd = blockIdx.x & 7, kkb = blockIdx.x >> 3;
    const int b = xcd >> 1;
    const int jb = (((xcd & 1) * (Jb >> 3)) + kkb) * 4 + wid;
    int i = 0;
    #pragma unroll 1
    for (; i + 1 < NG; ++i)
        if (jb < (Gp * (i + 1) * (i + 2)) >> 1) break;
    const int off = jb - ((Gp * i * (i + 1)) >> 1);
    const int c = off / Gp;
    const int qt = i * Gp + (off & (Gp - 1));
    const int q0 = qt * 32;
    const int klen = q0 + 32;
    const int k_lo = c * C;
    const int k_hi = min(k_lo + C, klen);
    const int nch = i + 1;

    const int rbq = b * 256 + qt * 2;
    u16x8 qf0[4], qf1[4];
    #pragma unroll
    for (int ds = 0; ds < 4; ++ds) {
        qf0[ds] = *(const u16x8*)&Qf[(((size_t)rbq * 4 + ds) * 64 + lane) * 8];
        qf1[ds] = *(const u16x8*)&Qf[(((size_t)(rbq + 1) * 4 + ds) * 64 + lane) * 8];
    }

    const f32x4 fz = {0.f, 0.f, 0.f, 0.f};
    f32x4 o0[8], o1[8];
    #pragma unroll
    for (int e = 0; e < 8; ++e) { o0[e] = fz; o1[e] = fz; }
    float m0 = -3e38f, m1 = -3e38f, l0 = 0.f, l1 = 0.f;

    const int srcA = l16 + ((g & 1) << 5);
    const int srcB = srcA + 16;
    const bool hiSel = (g >= 2);

    for (int k0 = k_lo; k0 < k_hi; k0 += 64) {
        // ---- S^T = K * Q^T for both q-halves (K frags shared) ----
        const size_t kbase = ((size_t)(b * 256 + (k0 >> 4)) * 4) * 64 * 8;
        f32x4 st0[4], st1[4];
        #pragma unroll
        for (int kt = 0; kt < 4; ++kt) {
            st0[kt] = fz; st1[kt] = fz;
            #pragma unroll
            for (int ds = 0; ds < 4; ++ds) {
                u16x8 kf = *(const u16x8*)&Kf[kbase + ((kt * 4 + ds) * 64 + lane) * 8];
                st0[kt] = mfma16(kf, qf0[ds], st0[kt]);
                st1[kt] = mfma16(kf, qf1[ds], st1[kt]);
            }
        }
        // ---- causal mask (diagonal tiles only), per half ----
        if (k0 + 63 > q0) {
            int qg = q0 + l16;
            #pragma unroll
            for (int kt = 0; kt < 4; ++kt)
                #pragma unroll
                for (int r = 0; r < 4; ++r)
                    if (k0 + kt * 16 + g * 4 + r > qg) st0[kt][r] = -1e30f;
        }
        if (k0 + 63 > q0 + 16) {
            int qg = q0 + 16 + l16;
            #pragma unroll
            for (int kt = 0; kt < 4; ++kt)
                #pragma unroll
                for (int r = 0; r < 4; ++r)
                    if (k0 + kt * 16 + g * 4 + r > qg) st1[kt][r] = -1e30f;
        }
        // ---- online softmax, log2 domain, defer-rescale ----
        u32 pk0[4][2], pk1[4][2];
        {
            float pm = -3e38f;
            #pragma unroll
            for (int kt = 0; kt < 4; ++kt)
                pm = fmaxf(pm, fmaxf(fmaxf(st0[kt][0], st0[kt][1]), fmaxf(st0[kt][2], st0[kt][3])));
            pm = fmaxf(pm, __shfl_xor(pm, 16));
            pm = fmaxf(pm, __shfl_xor(pm, 32));
            if (!__all(pm - m0 <= 10.0f)) {
                float mnew = fmaxf(m0, pm);
                float alpha = exp2f(m0 - mnew);
                l0 *= alpha;
                #pragma unroll
                for (int e = 0; e < 8; ++e)
                    #pragma unroll
                    for (int r = 0; r < 4; ++r) o0[e][r] *= alpha;
                m0 = mnew;
            }
            float lsum = 0.f;
            #pragma unroll
            for (int kt = 0; kt < 4; ++kt) {
                float p0 = exp2f(st0[kt][0] - m0), p1 = exp2f(st0[kt][1] - m0);
                float p2 = exp2f(st0[kt][2] - m0), p3 = exp2f(st0[kt][3] - m0);
                lsum += (p0 + p1) + (p2 + p3);
                pk0[kt][0] = cvtpk(p0, p1);
                pk0[kt][1] = cvtpk(p2, p3);
            }
            lsum += __shfl_xor(lsum, 16);
            lsum += __shfl_xor(lsum, 32);
            l0 += lsum;
        }
        {
            float pm = -3e38f;
            #pragma unroll
            for (int kt = 0; kt < 4; ++kt)
                pm = fmaxf(pm, fmaxf(fmaxf(st1[kt][0], st1[kt][1]), fmaxf(st1[kt][2], st1[kt][3])));
            pm = fmaxf(pm, __shfl_xor(pm, 16));
            pm = fmaxf(pm, __shfl_xor(pm, 32));
            if (!__all(pm - m1 <= 10.0f)) {
                float mnew = fmaxf(m1, pm);
                float alpha = exp2f(m1 - mnew);
                l1 *= alpha;
                #pragma unroll
                for (int e = 0; e < 8; ++e)
                    #pragma unroll
                    for (int r = 0; r < 4; ++r) o1[e][r] *= alpha;
                m1 = mnew;
            }
            float lsum = 0.f;
            #pragma unroll
            for (int kt = 0; kt < 4; ++kt) {
                float p0 = exp2f(st1[kt][0] - m1), p1 = exp2f(st1[kt][1] - m1);
                float p2 = exp2f(st1[kt][2] - m1), p3 = exp2f(st1[kt][3] - m1);
                lsum += (p0 + p1) + (p2 + p3);
                pk1[kt][0] = cvtpk(p0, p1);
                pk1[kt][1] = cvtpk(p2, p3);
            }
            lsum += __shfl_xor(lsum, 16);
            lsum += __shfl_xor(lsum, 32);
            l1 += lsum;
        }
        // ---- P redistribute (in-register) + O^T += V^T * P^T (V frags shared) ----
        #pragma unroll
        for (int ksel = 0; ksel < 2; ++ksel) {
            u32 a0 = __shfl((int)pk0[2 * ksel][0], srcA), b0 = __shfl((int)pk0[2 * ksel + 1][0], srcA);
            u32 a1 = __shfl((int)pk0[2 * ksel][1], srcA), b1 = __shfl((int)pk0[2 * ksel + 1][1], srcA);
            u32 a2 = __shfl((int)pk0[2 * ksel][0], srcB), b2 = __shfl((int)pk0[2 * ksel + 1][0], srcB);
            u32 a3 = __shfl((int)pk0[2 * ksel][1], srcB), b3 = __shfl((int)pk0[2 * ksel + 1][1], srcB);
            u32x4 d0 = { hiSel ? b0 : a0, hiSel ? b1 : a1, hiSel ? b2 : a2, hiSel ? b3 : a3 };
            u16x8 pf0 = __builtin_bit_cast(u16x8, d0);
            u32 c0 = __shfl((int)pk1[2 * ksel][0], srcA), e0 = __shfl((int)pk1[2 * ksel + 1][0], srcA);
            u32 c1 = __shfl((int)pk1[2 * ksel][1], srcA), e1 = __shfl((int)pk1[2 * ksel + 1][1], srcA);
            u32 c2 = __shfl((int)pk1[2 * ksel][0], srcB), e2 = __shfl((int)pk1[2 * ksel + 1][0], srcB);
            u32 c3 = __shfl((int)pk1[2 * ksel][1], srcB), e3 = __shfl((int)pk1[2 * ksel + 1][1], srcB);
            u32x4 d1 = { hiSel ? e0 : c0, hiSel ? e1 : c1, hiSel ? e2 : c2, hiSel ? e3 : c3 };
            u16x8 pf1 = __builtin_bit_cast(u16x8, d1);
            const size_t vbase = (((size_t)(b * 64 + (k0 >> 6)) * 2 + ksel) * 8) * 64 * 8;
            #pragma unroll
            for (int e = 0; e < 8; ++e) {
                u16x8 vf = *(const u16x8*)&Vf[vbase + (e * 64 + lane) * 8];
                o0[e] = mfma16(vf, pf0, o0[e]);
                o1[e] = mfma16(vf, pf1, o1[e]);
            }
        }
    }

    if (nch == 1) {
        float inv0 = 1.0f / l0, inv1 = 1.0f / l1;
        float* op0 = out + ((size_t)b * 4096 + q0 + l16) * 128;
        float* op1 = out + ((size_t)b * 4096 + q0 + 16 + l16) * 128;
        #pragma unroll
        for (int e = 0; e < 8; ++e) {
            f32x4 v0 = o0[e], v1 = o1[e];
            #pragma unroll
            for (int r = 0; r < 4; ++r) { v0[r] *= inv0; v1[r] *= inv1; }
            *(f32x4*)&op0[e * 16 + g * 4] = v0;
            *(f32x4*)&op1[e * 16 + g * 4] = v1;
        }
    } else {
        const int slot = b * Jb + jb;
        u16* pp0 = po + ((size_t)slot * 32 + l16) * 128;
        u16* pp1 = po + ((size_t)slot * 32 + 16 + l16) * 128;
        #pragma unroll
        for (int e = 0; e < 8; ++e) {
            u16x4 v0, v1;
            #pragma unroll
            for (int r = 0; r < 4; ++r) { v0[r] = f2bf(o0[e][r]); v1[r] = f2bf(o1[e][r]); }
            *(u16x4*)&pp0[e * 16 + g * 4] = v0;
            *(u16x4*)&pp1[e * 16 + g * 4] = v1;
        }
        if (g == 0) {
            pml[(size_t)slot * 32 + l16] = make_float2(m0, l0);
            pml[(size_t)slot * 32 + 16 + l16] = make_float2(m1, l1);
        }
    }
}

// ---------------------------------------------------------------------------
// Kernel 4: merge split-K partials (qt >= Gp). 1 thread = 4 cols. log2 weights.
// ---------------------------------------------------------------------------
__global__ __launch_bounds__(256) void merge4(
    const u16* __restrict__ po, const float2* __restrict__ pml,
    float* __restrict__ out, int Gp, int Jb, int rows_per_b)
{
    int gid = blockIdx.x * 256 + threadIdx.x;
    int colg = gid & 31;
    int r = gid >> 5;
    int b = r / rows_per_b;
    int rr = r - b * rows_per_b;
    int qt = (rr >> 5) + Gp;
    int qr = rr & 31;
    int i = qt / Gp;
    int nch = i + 1;
    int slot0 = b * Jb + ((Gp * i * (i + 1)) >> 1) + (qt - i * Gp);

    float ms = -3e38f;
    #pragma unroll 1
    for (int c = 0; c < nch; ++c)
        ms = fmaxf(ms, pml[(size_t)(slot0 + c * Gp) * 32 + qr].x);
    float den = 0.f;
    f32x4 num = {0.f, 0.f, 0.f, 0.f};
    #pragma unroll 1
    for (int c = 0; c < nch; ++c) {
        int slot = slot0 + c * Gp;
        float2 ml = pml[(size_t)slot * 32 + qr];
        float w = exp2f(ml.x - ms);
        den += w * ml.y;
        u16x4 pv = *(const u16x4*)&po[((size_t)slot * 32 + qr) * 128 + colg * 4];
        #pragma unroll
        for (int j = 0; j < 4; ++j) num[j] += w * bf2f(pv[j]);
    }
    float inv = 1.0f / den;
    f32x4 res = { num[0] * inv, num[1] * inv, num[2] * inv, num[3] * inv };
    *(f32x4*)&out[((size_t)b * 4096 + qt * 32 + qr) * 128 + colg * 4] = res;
}

extern "C" void kernel_launch(void* const* d_in, const int* in_sizes, int n_in,
                              void* d_out, int out_size, void* d_ws, size_t ws_size,
                              hipStream_t stream) {
    (void)in_sizes; (void)n_in; (void)out_size;
    const float* x  = (const float*)d_in[0];
    const float* Wq = (const float*)d_in[1];
    const float* Wk = (const float*)d_in[2];
    const float* Wv = (const float*)d_in[3];
    float* out = (float*)d_out;

    u16* xf = (u16*)d_ws;                    //  8,388,608 u16 (16 MB)
    u16* wf = xf + 8388608;                  //    196,608 u16
    u16* Qf = wf + 196608;                   //  2,097,152 u16 each
    u16* Kf = Qf + 2097152;
    u16* Vf = Kf + 2097152;
    u16* po = Vf + 2097152;
    const size_t base_bytes = (size_t)(8388608 + 196608 + 3 * 2097152) * 2; // 29,753,344

    // split-K ladder: Jb = Gp*NG*(NG+1)/2 per batch, Gp = C/32, slots = 4*Jb
    auto need = [base_bytes](int Jb) {
        return base_bytes + (size_t)4 * Jb * (32 * 128 * 2 + 32 * 8);
    };
    int C, Jb_;
    if      (ws_size >= need(1088)) { C = 256;  Jb_ = 1088; }
    else if (ws_size >= need(576))  { C = 512;  Jb_ = 576;  }
    else if (ws_size >= need(320))  { C = 1024; Jb_ = 320;  }
    else if (ws_size >= need(192))  { C = 2048; Jb_ = 192;  }
    else                            { C = 4096; Jb_ = 128;  }
    const int Gp = C / 32, NG = 4096 / C;
    float2* pml = (float2*)(po + (size_t)4 * Jb_ * 32 * 128);

    prep_w<<<96, 256, 0, stream>>>(Wq, Wk, Wv, wf);
    prep_x<<<1024, 256, 0, stream>>>(x, xf);
    qkv2<<<dim3(128, 3), 256, 0, stream>>>(xf, wf, Qf, Kf, Vf);
    attn4<<<Jb_, 256, 0, stream>>>(Qf, Kf, Vf, out, po, pml, C, Gp, NG, Jb_);
    if (NG > 1) {
        const int rows_per_b = (128 - Gp) * 32;
        merge4<<<rows_per_b / 2, 256, 0, stream>>>(po, pml, out, Gp, Jb_, rows_per_b);
    }
}